// Round 5
// baseline (715.418 us; speedup 1.0000x reference)
//
#include <hip/hip_runtime.h>
#include <math.h>

#define PI_LEN 0.3141592653589793f   // pi / 10.0
#define LEN_F  10.0f
#define TBL    4096                   // table rows = TBL+1

__device__ __forceinline__ float fsilu(float x) {
  return x * __builtin_amdgcn_rcpf(1.f + __expf(-x));
}

// ---------------------------------------------------------------------------
// CSR build: hist -> scan -> scatter (edge_index constant across layers)
// ---------------------------------------------------------------------------
__global__ __launch_bounds__(256) void hist_kernel(const int* __restrict__ ei,
                                                   int* __restrict__ deg, int E_) {
  int e = blockIdx.x * 256 + threadIdx.x;
  if (e < E_) atomicAdd(&deg[ei[E_ + e]], 1);
}

__global__ __launch_bounds__(1024) void scan_kernel(const int* __restrict__ deg,
                                                    int* __restrict__ off,
                                                    int* __restrict__ cursor, int N_) {
  __shared__ int wtot[16];
  __shared__ int carry_s;
  int tid = threadIdx.x, lane = tid & 63, wid = tid >> 6;
  if (tid == 0) carry_s = 0;
  __syncthreads();
  int nch = (N_ + 8191) / 8192;
  for (int c = 0; c < nch; ++c) {
    int base_idx = c * 8192 + tid * 8;
    int x[8]; int mysum = 0;
    #pragma unroll
    for (int j = 0; j < 8; ++j) { int idx = base_idx + j; x[j] = (idx < N_) ? deg[idx] : 0; mysum += x[j]; }
    int incl = mysum;
    #pragma unroll
    for (int s = 1; s < 64; s <<= 1) { int t = __shfl_up(incl, s, 64); if (lane >= s) incl += t; }
    if (lane == 63) wtot[wid] = incl;
    __syncthreads();
    if (wid == 0) {
      int wt = (lane < 16) ? wtot[lane] : 0;
      #pragma unroll
      for (int s = 1; s < 16; s <<= 1) { int t = __shfl_up(wt, s, 64); if (lane >= s) wt += t; }
      if (lane < 16) wtot[lane] = wt;
    }
    __syncthreads();
    int wexcl = (wid > 0) ? wtot[wid - 1] : 0;
    int run = carry_s + wexcl + (incl - mysum);
    #pragma unroll
    for (int j = 0; j < 8; ++j) {
      int idx = base_idx + j;
      if (idx < N_) { off[idx] = run; cursor[idx] = run; }
      run += x[j];
    }
    __syncthreads();
    if (tid == 0) carry_s += wtot[15];
    __syncthreads();
  }
  if (tid == 0) off[N_] = carry_s;
}

__global__ __launch_bounds__(256) void scatter_kernel(
    const int* __restrict__ ei, const float* __restrict__ dist,
    const float* __restrict__ edir, int* __restrict__ cursor,
    int* __restrict__ srcp, float4* __restrict__ edata, int E_) {
  int e = blockIdx.x * 256 + threadIdx.x;
  if (e < E_) {
    int dst = ei[E_ + e];
    int pos = atomicAdd(&cursor[dst], 1);
    srcp[pos] = ei[e];
    edata[pos] = make_float4(edir[3*e], edir[3*e+1], edir[3*e+2], dist[e]);
  }
}

// ---------------------------------------------------------------------------
// shared helper: filter-table block (8 t-rows per block, half-wave-private
// LDS rows -> no barriers needed; wave64 lockstep orders ds ops)
// ---------------------------------------------------------------------------
__device__ __forceinline__ void mlp_tbl_block(
    int i, int g, int t,
    const float* __restrict__ w1, const float* __restrict__ b1,
    const float* __restrict__ w2, const float* __restrict__ b2,
    float4* __restrict__ tbl4, float (*pe)[96], float (*hl)[32])
{
  bool okt = (t <= TBL);
  float d = (float)t * (LEN_F / (float)TBL);
  pe[i][g] = (g < 16) ? __sinf(d * (float)(g + 1) * PI_LEN)
                      : __cosf(d * (float)(g - 15) * PI_LEN);
  float h = b1[g];
  for (int k = 0; k < 32; ++k) h += pe[i][k] * w1[k*32 + g];
  hl[i][g] = fsilu(h);
  float o0 = b2[g], o1 = b2[32+g], o2 = b2[64+g], o3 = b2[96+g];
  for (int k = 0; k < 32; ++k) {
    float hk = hl[i][k];
    o0 += hk * w2[k*128 +      g];
    o1 += hk * w2[k*128 + 32 + g];
    o2 += hk * w2[k*128 + 64 + g];
    o3 += hk * w2[k*128 + 96 + g];
  }
  if (okt) tbl4[(long)t*32 + g] = make_float4(o0, o1, o2, o3);
}

// ---------------------------------------------------------------------------
// layer0 prep: blocks [0,nodeBlocks) -> Aout4 from s_in; rest -> tbl l0
// Aout4[n*32+g] = (gates, cpg, sed, sf * s[n][g])
// ---------------------------------------------------------------------------
__global__ __launch_bounds__(256) void nodeA_tbl_kernel(
    const float* __restrict__ s,
    const float* __restrict__ mpw1, const float* __restrict__ mpb1,
    const float* __restrict__ mpw2, const float* __restrict__ mpb2,
    const float* __restrict__ mww1, const float* __restrict__ mwb1,
    const float* __restrict__ mww2, const float* __restrict__ mwb2,
    float4* __restrict__ Aout4, float4* __restrict__ tbl4,
    int N_, int nodeBlocks)
{
  __shared__ float a[8][96];
  __shared__ float c[8][32];
  int tid = threadIdx.x, i = tid >> 5, g = tid & 31;
  if (blockIdx.x >= nodeBlocks) {
    int t = (blockIdx.x - nodeBlocks) * 8 + i;
    mlp_tbl_block(i, g, t, mww1, mwb1, mww2, mwb2, tbl4, a, c);
    return;
  }
  long n = (long)blockIdx.x * 8 + i;
  bool ok = (n < N_);
  a[i][g] = ok ? s[n*32 + g] : 0.f;
  float h = mpb1[g];
  for (int k = 0; k < 32; ++k) h += a[i][k] * mpw1[k*32 + g];
  c[i][g] = fsilu(h);
  float o0 = mpb2[g], o1 = mpb2[32+g], o2 = mpb2[64+g], o3 = mpb2[96+g];
  for (int k = 0; k < 32; ++k) {
    float hk = c[i][k];
    o0 += hk * mpw2[k*128 +      g];
    o1 += hk * mpw2[k*128 + 32 + g];
    o2 += hk * mpw2[k*128 + 64 + g];
    o3 += hk * mpw2[k*128 + 96 + g];
  }
  if (ok) Aout4[n*32 + g] = make_float4(o0, o1, o2, o3 * a[i][g]);
}

// ---------------------------------------------------------------------------
// gather: barrier-free, 4 nodes/block, one wave64/node, lane=(hf,g).
// Batch 8 edges per half-wave (16/wave) with clamped+masked loads so most
// nodes (avg deg 16) take ONE latency exposure.
// Writes acc4[n*32+g] = (av0, av1, av2, acc_s).
// ---------------------------------------------------------------------------
#define EDGE_MATH_M(ED, M0, M1, FR, MS, Av, V0, V1, V2)                    \
  {                                                                        \
    float ga = (M0.x + FR*(M1.x - M0.x)) * MS;                             \
    float ca = (M0.y + FR*(M1.y - M0.y)) * MS;                             \
    float da = (M0.z + FR*(M1.z - M0.z)) * MS;                             \
    float sa = (M0.w + FR*(M1.w - M0.w)) * MS;                             \
    float gates = ga*Av.x, cpg = ca*Av.y, sed = da*Av.z;                   \
    acc_s += sa*Av.w;                                                      \
    float crx = ED.y*vd2 - ED.z*vd1;                                       \
    float cry = ED.z*vd0 - ED.x*vd2;                                       \
    float crz = ED.x*vd1 - ED.y*vd0;                                       \
    av0 += sed*ED.x + gates*V0 + cpg*crx;                                  \
    av1 += sed*ED.y + gates*V1 + cpg*cry;                                  \
    av2 += sed*ED.z + gates*V2 + cpg*crz;                                  \
  }

__global__ __launch_bounds__(256) void gather_kernel(
    const int* __restrict__ off, const int* __restrict__ srcp,
    const float4* __restrict__ edata, const float4* __restrict__ tbl4,
    const float* __restrict__ v_prev, const float4* __restrict__ Aout4,
    float4* __restrict__ acc4, int N_)
{
  int tid = threadIdx.x, w = tid >> 6, lane = tid & 63, g = lane & 31, hf = lane >> 5;
  int n = blockIdx.x * 4 + w;
  if (n >= N_) return;                      // no barriers: early exit is safe
  const float* vp = v_prev + (long)n*96 + g*3;
  float vd0 = vp[0], vd1 = vp[1], vd2 = vp[2];
  int pstart = off[n], pend = off[n + 1];
  float acc_s = 0, av0 = 0, av1 = 0, av2 = 0;
  const float inv_step = (float)TBL / LEN_F;

  for (int p0 = pstart + hf * 8; p0 < pend; p0 += 16) {
    int cnt = pend - p0; if (cnt > 8) cnt = 8;     // 1..8 valid this round
    int idx[8]; float4 ed[8];
    #pragma unroll
    for (int b = 0; b < 8; ++b) {
      int p = (b < cnt) ? p0 + b : p0;
      idx[b] = srcp[p];
      ed[b]  = edata[p];
    }
    float4 m0[8], m1[8], A[8]; float fr[8];
    float vs0[8], vs1[8], vs2[8];
    #pragma unroll
    for (int b = 0; b < 8; ++b) {
      float x = ed[b].w * inv_step;
      float f = floorf(x);
      int i0 = (int)f; if (i0 > TBL - 1) i0 = TBL - 1;
      fr[b] = x - f;
      m0[b] = tbl4[(long)i0*32 + g];
      m1[b] = tbl4[(long)(i0 + 1)*32 + g];
      A[b]  = Aout4[(long)idx[b]*32 + g];
      const float* vq = v_prev + (long)idx[b]*96 + g*3;
      vs0[b] = vq[0]; vs1[b] = vq[1]; vs2[b] = vq[2];
    }
    #pragma unroll
    for (int b = 0; b < 8; ++b) {
      float msk = (b < cnt) ? 1.f : 0.f;
      EDGE_MATH_M(ed[b], m0[b], m1[b], fr[b], msk, A[b], vs0[b], vs1[b], vs2[b]);
    }
  }
  av0   += __shfl_xor(av0, 32);
  av1   += __shfl_xor(av1, 32);
  av2   += __shfl_xor(av2, 32);
  acc_s += __shfl_xor(acc_s, 32);
  if (hf == 0) acc4[(long)n*32 + g] = make_float4(av0, av1, av2, acc_s);
}

// ---------------------------------------------------------------------------
// update (layer 0) + nodeA for layer 1 fused in tail; extra blocks do tbl l1.
// All LDS rows are half-wave-private -> no barriers (wave64 lockstep).
// ---------------------------------------------------------------------------
__global__ __launch_bounds__(256) void update_mid_kernel(
    const float* __restrict__ s_prev, const float* __restrict__ v_prev,
    const float4* __restrict__ acc4,
    const float* __restrict__ uU, const float* __restrict__ uV,
    const float* __restrict__ uw1, const float* __restrict__ ub1,
    const float* __restrict__ uw2, const float* __restrict__ ub2,
    const float* __restrict__ nw1, const float* __restrict__ nb1,
    const float* __restrict__ nw2, const float* __restrict__ nb2,
    const float* __restrict__ tw1, const float* __restrict__ tb1,
    const float* __restrict__ tw2, const float* __restrict__ tb2,
    float* __restrict__ s_out, float* __restrict__ v_out,
    float4* __restrict__ Aout4, float4* __restrict__ tbl4,
    int N_, int nodeBlocks)
{
  __shared__ float vld[8][96];
  __shared__ float in64[8][64];
  __shared__ float hld[8][32];
  int tid = threadIdx.x, i = tid >> 5, g = tid & 31;
  if (blockIdx.x >= nodeBlocks) {
    int t = (blockIdx.x - nodeBlocks) * 8 + i;
    mlp_tbl_block(i, g, t, tw1, tb1, tw2, tb2, tbl4, vld, hld);
    return;
  }
  long n = (long)blockIdx.x * 8 + i;
  bool ok = (n < N_);
  float nv0 = 0, nv1 = 0, nv2 = 0, ns = 0;
  if (ok) {
    float4 a = acc4[n*32 + g];
    const float* vp = v_prev + n*96 + g*3;
    nv0 = vp[0] + a.x; nv1 = vp[1] + a.y; nv2 = vp[2] + a.z;
    ns  = s_prev[n*32 + g] + a.w;
  }
  vld[i][g*3+0] = nv0; vld[i][g*3+1] = nv1; vld[i][g*3+2] = nv2;
  float Vv0=0,Vv1=0,Vv2=0,Uv0=0,Uv1=0,Uv2=0;
  for (int f = 0; f < 32; ++f) {
    float wu = uU[f*32 + g];
    float wv = uV[f*32 + g];
    float v0 = vld[i][f*3+0], v1 = vld[i][f*3+1], v2 = vld[i][f*3+2];
    Vv0 += v0*wv; Vv1 += v1*wv; Vv2 += v2*wv;
    Uv0 += v0*wu; Uv1 += v1*wu; Uv2 += v2*wu;
  }
  float Vn = sqrtf(Vv0*Vv0 + Vv1*Vv1 + Vv2*Vv2);
  in64[i][g] = Vn; in64[i][32 + g] = ns;
  float h = ub1[g];
  for (int k = 0; k < 64; ++k) h += in64[i][k] * uw1[k*32 + g];
  h = fsilu(h);
  hld[i][g] = h;
  float og = ub2[g], ossn = ub2[32 + g], oadd = ub2[64 + g];
  for (int k = 0; k < 32; ++k) {
    float hk = hld[i][k];
    og   += hk * uw2[k*96 +      g];
    ossn += hk * uw2[k*96 + 32 + g];
    oadd += hk * uw2[k*96 + 64 + g];
  }
  float s_fin = ns + Vn*Vn*ossn + oadd;
  if (ok) {
    float* vo = v_out + n*96 + g*3;
    vo[0] = nv0 + og*Uv0;
    vo[1] = nv1 + og*Uv1;
    vo[2] = nv2 + og*Uv2;
    s_out[n*32 + g] = s_fin;
  }
  // ---- nodeA for layer 1 (input = s_fin) ----
  in64[i][g] = s_fin;                          // reuse as x-stage
  float h2 = nb1[g];
  for (int k = 0; k < 32; ++k) h2 += in64[i][k] * nw1[k*32 + g];
  h2 = fsilu(h2);
  hld[i][g] = h2;
  float o0 = nb2[g], o1 = nb2[32+g], o2 = nb2[64+g], o3 = nb2[96+g];
  for (int k = 0; k < 32; ++k) {
    float hk = hld[i][k];
    o0 += hk * nw2[k*128 +      g];
    o1 += hk * nw2[k*128 + 32 + g];
    o2 += hk * nw2[k*128 + 64 + g];
    o3 += hk * nw2[k*128 + 96 + g];
  }
  if (ok) Aout4[n*32 + g] = make_float4(o0, o1, o2, o3 * s_fin);
}

// ---------------------------------------------------------------------------
// update (layer 1) + readout fused: writes d_out directly, never writes s/v.
// ---------------------------------------------------------------------------
__global__ __launch_bounds__(256) void update_final_kernel(
    const float* __restrict__ s_prev, const float* __restrict__ v_prev,
    const float4* __restrict__ acc4,
    const float* __restrict__ uU, const float* __restrict__ uV,
    const float* __restrict__ uw1, const float* __restrict__ ub1,
    const float* __restrict__ uw2, const float* __restrict__ ub2,
    const float* __restrict__ rw1, const float* __restrict__ rb1,
    const float* __restrict__ rw2, const float* __restrict__ rb2,
    const float* __restrict__ roV, float* __restrict__ out, int N_)
{
  __shared__ float vld[8][96];
  __shared__ float in64[8][64];
  __shared__ float hld[8][32];
  int tid = threadIdx.x, i = tid >> 5, g = tid & 31;
  long n = (long)blockIdx.x * 8 + i;
  bool ok = (n < N_);
  float nv0 = 0, nv1 = 0, nv2 = 0, ns = 0;
  if (ok) {
    float4 a = acc4[n*32 + g];
    const float* vp = v_prev + n*96 + g*3;
    nv0 = vp[0] + a.x; nv1 = vp[1] + a.y; nv2 = vp[2] + a.z;
    ns  = s_prev[n*32 + g] + a.w;
  }
  vld[i][g*3+0] = nv0; vld[i][g*3+1] = nv1; vld[i][g*3+2] = nv2;
  float Vv0=0,Vv1=0,Vv2=0,Uv0=0,Uv1=0,Uv2=0;
  for (int f = 0; f < 32; ++f) {
    float wu = uU[f*32 + g];
    float wv = uV[f*32 + g];
    float v0 = vld[i][f*3+0], v1 = vld[i][f*3+1], v2 = vld[i][f*3+2];
    Vv0 += v0*wv; Vv1 += v1*wv; Vv2 += v2*wv;
    Uv0 += v0*wu; Uv1 += v1*wu; Uv2 += v2*wu;
  }
  float Vn = sqrtf(Vv0*Vv0 + Vv1*Vv1 + Vv2*Vv2);
  in64[i][g] = Vn; in64[i][32 + g] = ns;
  float h = ub1[g];
  for (int k = 0; k < 64; ++k) h += in64[i][k] * uw1[k*32 + g];
  h = fsilu(h);
  hld[i][g] = h;
  float og = ub2[g], ossn = ub2[32 + g], oadd = ub2[64 + g];
  for (int k = 0; k < 32; ++k) {
    float hk = hld[i][k];
    og   += hk * uw2[k*96 +      g];
    ossn += hk * uw2[k*96 + 32 + g];
    oadd += hk * uw2[k*96 + 64 + g];
  }
  float s_fin = ns + Vn*Vn*ossn + oadd;
  float vf0 = nv0 + og*Uv0, vf1 = nv1 + og*Uv1, vf2 = nv2 + og*Uv2;
  // ---- readout ----
  in64[i][g] = s_fin;
  float h2 = rb1[g];
  for (int k = 0; k < 32; ++k) h2 += in64[i][k] * rw1[k*32 + g];
  h2 = fsilu(h2);
  hld[i][g] = h2;
  float inv = rb2[g], gate = rb2[32 + g];
  for (int k = 0; k < 32; ++k) {
    float hk = hld[i][k];
    inv  += hk * rw2[k*64 +      g];
    gate += hk * rw2[k*64 + 32 + g];
  }
  vld[i][g*3+0] = vf0; vld[i][g*3+1] = vf1; vld[i][g*3+2] = vf2;
  float R0 = 0, R1 = 0, R2 = 0;
  for (int f = 0; f < 32; ++f) {
    float wv = roV[f*32 + g];
    R0 += vld[i][f*3+0]*wv; R1 += vld[i][f*3+1]*wv; R2 += vld[i][f*3+2]*wv;
  }
  if (ok) {
    out[n*32 + g] = inv;
    long eb = (long)N_*32 + n*96 + (long)g*3;
    out[eb+0] = gate*R0; out[eb+1] = gate*R1; out[eb+2] = gate*R2;
  }
}

// ---------------------------------------------------------------------------
extern "C" void kernel_launch(void* const* d_in, const int* in_sizes, int n_in,
                              void* d_out, int out_size, void* d_ws, size_t ws_size,
                              hipStream_t stream)
{
  const float* s_in  = (const float*)d_in[0];
  const float* v_in  = (const float*)d_in[1];   // (N, F, 3)
  const int*   ei    = (const int*)  d_in[2];
  const float* dist  = (const float*)d_in[3];
  const float* edir  = (const float*)d_in[4];
  const float* mp_w1 = (const float*)d_in[5];
  const float* mp_b1 = (const float*)d_in[6];
  const float* mp_w2 = (const float*)d_in[7];
  const float* mp_b2 = (const float*)d_in[8];
  const float* mw_w1 = (const float*)d_in[9];
  const float* mw_b1 = (const float*)d_in[10];
  const float* mw_w2 = (const float*)d_in[11];
  const float* mw_b2 = (const float*)d_in[12];
  const float* u_U   = (const float*)d_in[13];
  const float* u_V   = (const float*)d_in[14];
  const float* u_w1  = (const float*)d_in[15];
  const float* u_b1  = (const float*)d_in[16];
  const float* u_w2  = (const float*)d_in[17];
  const float* u_b2  = (const float*)d_in[18];
  const float* ro_w1 = (const float*)d_in[19];
  const float* ro_b1 = (const float*)d_in[20];
  const float* ro_w2 = (const float*)d_in[21];
  const float* ro_b2 = (const float*)d_in[22];
  const float* ro_V  = (const float*)d_in[23];

  int N_ = in_sizes[0] / 32;
  int E_ = in_sizes[3];

  float*  sB    = (float*)d_ws;                       // N*32
  float*  vB    = sB + (size_t)N_*32;                 // N*96
  float4* Aout4 = (float4*)(vB + (size_t)N_*96);      // N*32 float4
  float4* acc4b = Aout4 + (size_t)N_*32;              // N*32 float4 (layer-1 acc)
  float4* tbl4  = acc4b + (size_t)N_*32;              // (TBL+1)*32 float4
  float4* edata = tbl4 + (size_t)(TBL+1)*32;          // E float4
  int*    srcp  = (int*)(edata + (size_t)E_);         // E
  int*    deg   = srcp + E_;                          // N
  int*    off   = deg + N_;                           // N+1
  int*    cursor= off + N_ + 1;                       // N

  // layer-0 acc scratch: d_out (N*32 float4) — fully dead before final write.
  float4* acc4a = (float4*)d_out;

  int nodeBlocks = (N_ + 7) / 8;
  int gathBlocks = (N_ + 3) / 4;
  int edgeBlocks = (E_ + 255) / 256;
  int tblBlocks  = (TBL + 1 + 7) / 8;

  // --- CSR build (once; edge_index constant across layers) ---
  hipMemsetAsync(deg, 0, (size_t)N_ * sizeof(int), stream);
  hist_kernel<<<edgeBlocks, 256, 0, stream>>>(ei, deg, E_);
  scan_kernel<<<1, 1024, 0, stream>>>(deg, off, cursor, N_);
  scatter_kernel<<<edgeBlocks, 256, 0, stream>>>(ei, dist, edir, cursor, srcp, edata, E_);

  // --- layer 0 prep: Aout(l0) + tbl(l0) in one launch ---
  nodeA_tbl_kernel<<<nodeBlocks + tblBlocks, 256, 0, stream>>>(
      s_in, mp_w1, mp_b1, mp_w2, mp_b2, mw_w1, mw_b1, mw_w2, mw_b2,
      Aout4, tbl4, N_, nodeBlocks);

  gather_kernel<<<gathBlocks, 256, 0, stream>>>(
      off, srcp, edata, tbl4, v_in, Aout4, acc4a, N_);

  // --- update l0 + nodeA(l1) + tbl(l1) ---
  update_mid_kernel<<<nodeBlocks + tblBlocks, 256, 0, stream>>>(
      s_in, v_in, acc4a,
      u_U, u_V, u_w1, u_b1, u_w2, u_b2,
      mp_w1 + 1024, mp_b1 + 32, mp_w2 + 4096, mp_b2 + 128,
      mw_w1 + 1024, mw_b1 + 32, mw_w2 + 4096, mw_b2 + 128,
      sB, vB, Aout4, tbl4, N_, nodeBlocks);

  gather_kernel<<<gathBlocks, 256, 0, stream>>>(
      off, srcp, edata, tbl4, vB, Aout4, acc4b, N_);

  // --- update l1 + readout ---
  update_final_kernel<<<nodeBlocks, 256, 0, stream>>>(
      sB, vB, acc4b,
      u_U + 1024, u_V + 1024, u_w1 + 2048, u_b1 + 32, u_w2 + 3072, u_b2 + 96,
      ro_w1, ro_b1, ro_w2, ro_b2, ro_V, (float*)d_out, N_);
}

// Round 6
// 632.721 us; speedup vs baseline: 1.1307x; 1.1307x over previous
//
#include <hip/hip_runtime.h>
#include <math.h>

#define PI_LEN 0.3141592653589793f   // pi / 10.0
#define LEN_F  10.0f
#define TBL    4096                   // table rows = TBL+1

__device__ __forceinline__ float fsilu(float x) {
  return x * __builtin_amdgcn_rcpf(1.f + __expf(-x));
}

// ---------------------------------------------------------------------------
// CSR build: hist -> scan -> (scatter fused into prep_kernel)
// ---------------------------------------------------------------------------
__global__ __launch_bounds__(256) void hist_kernel(const int* __restrict__ ei,
                                                   int* __restrict__ deg, int E_) {
  int e = blockIdx.x * 256 + threadIdx.x;
  if (e < E_) atomicAdd(&deg[ei[E_ + e]], 1);
}

__global__ __launch_bounds__(1024) void scan_kernel(const int* __restrict__ deg,
                                                    int* __restrict__ off,
                                                    int* __restrict__ cursor, int N_) {
  __shared__ int wtot[16];
  __shared__ int carry_s;
  int tid = threadIdx.x, lane = tid & 63, wid = tid >> 6;
  if (tid == 0) carry_s = 0;
  __syncthreads();
  int nch = (N_ + 8191) / 8192;
  for (int c = 0; c < nch; ++c) {
    int base_idx = c * 8192 + tid * 8;
    int x[8]; int mysum = 0;
    #pragma unroll
    for (int j = 0; j < 8; ++j) { int idx = base_idx + j; x[j] = (idx < N_) ? deg[idx] : 0; mysum += x[j]; }
    int incl = mysum;
    #pragma unroll
    for (int s = 1; s < 64; s <<= 1) { int t = __shfl_up(incl, s, 64); if (lane >= s) incl += t; }
    if (lane == 63) wtot[wid] = incl;
    __syncthreads();
    if (wid == 0) {
      int wt = (lane < 16) ? wtot[lane] : 0;
      #pragma unroll
      for (int s = 1; s < 16; s <<= 1) { int t = __shfl_up(wt, s, 64); if (lane >= s) wt += t; }
      if (lane < 16) wtot[lane] = wt;
    }
    __syncthreads();
    int wexcl = (wid > 0) ? wtot[wid - 1] : 0;
    int run = carry_s + wexcl + (incl - mysum);
    #pragma unroll
    for (int j = 0; j < 8; ++j) {
      int idx = base_idx + j;
      if (idx < N_) { off[idx] = run; cursor[idx] = run; }
      run += x[j];
    }
    __syncthreads();
    if (tid == 0) carry_s += wtot[15];
    __syncthreads();
  }
  if (tid == 0) off[N_] = carry_s;
}

// ---------------------------------------------------------------------------
// shared helper: filter-table block (8 t-rows per block, half-wave-private
// LDS rows -> no barriers needed; wave64 lockstep orders ds ops)
// ---------------------------------------------------------------------------
__device__ __forceinline__ void mlp_tbl_block(
    int i, int g, int t,
    const float* __restrict__ w1, const float* __restrict__ b1,
    const float* __restrict__ w2, const float* __restrict__ b2,
    float4* __restrict__ tbl4, float (*pe)[96], float (*hl)[32])
{
  bool okt = (t <= TBL);
  float d = (float)t * (LEN_F / (float)TBL);
  pe[i][g] = (g < 16) ? __sinf(d * (float)(g + 1) * PI_LEN)
                      : __cosf(d * (float)(g - 15) * PI_LEN);
  float h = b1[g];
  for (int k = 0; k < 32; ++k) h += pe[i][k] * w1[k*32 + g];
  hl[i][g] = fsilu(h);
  float o0 = b2[g], o1 = b2[32+g], o2 = b2[64+g], o3 = b2[96+g];
  for (int k = 0; k < 32; ++k) {
    float hk = hl[i][k];
    o0 += hk * w2[k*128 +      g];
    o1 += hk * w2[k*128 + 32 + g];
    o2 += hk * w2[k*128 + 64 + g];
    o3 += hk * w2[k*128 + 96 + g];
  }
  if (okt) tbl4[(long)t*32 + g] = make_float4(o0, o1, o2, o3);
}

// ---------------------------------------------------------------------------
// prep: one launch, three block roles (they overlap on the machine):
//   [0, edgeBlocks)                      -> CSR data scatter (random-write)
//   [edgeBlocks, edgeBlocks+nodeBlocks)  -> nodeA(l0) from s_in (VALU)
//   rest                                 -> filter table l0 (VALU)
// Aout4[n*32+g] = (gates, cpg, sed, sf * s[n][g])
// ---------------------------------------------------------------------------
__global__ __launch_bounds__(256) void prep_kernel(
    const int* __restrict__ ei, const float* __restrict__ dist,
    const float* __restrict__ edir, int* __restrict__ cursor,
    int* __restrict__ srcp, float4* __restrict__ edata,
    const float* __restrict__ s,
    const float* __restrict__ mpw1, const float* __restrict__ mpb1,
    const float* __restrict__ mpw2, const float* __restrict__ mpb2,
    const float* __restrict__ mww1, const float* __restrict__ mwb1,
    const float* __restrict__ mww2, const float* __restrict__ mwb2,
    float4* __restrict__ Aout4, float4* __restrict__ tbl4,
    int N_, int E_, int edgeBlocks, int nodeBlocks)
{
  __shared__ float a[8][96];
  __shared__ float c[8][32];
  int bid = blockIdx.x;
  if (bid < edgeBlocks) {                    // ---- scatter role ----
    int e = bid * 256 + threadIdx.x;
    if (e < E_) {
      int dst = ei[E_ + e];
      int pos = atomicAdd(&cursor[dst], 1);
      srcp[pos] = ei[e];
      edata[pos] = make_float4(edir[3*e], edir[3*e+1], edir[3*e+2], dist[e]);
    }
    return;
  }
  bid -= edgeBlocks;
  int tid = threadIdx.x, i = tid >> 5, g = tid & 31;
  if (bid >= nodeBlocks) {                   // ---- tbl role ----
    int t = (bid - nodeBlocks) * 8 + i;
    mlp_tbl_block(i, g, t, mww1, mwb1, mww2, mwb2, tbl4, a, c);
    return;
  }
  long n = (long)bid * 8 + i;                // ---- nodeA role ----
  bool ok = (n < N_);
  a[i][g] = ok ? s[n*32 + g] : 0.f;
  float h = mpb1[g];
  for (int k = 0; k < 32; ++k) h += a[i][k] * mpw1[k*32 + g];
  c[i][g] = fsilu(h);
  float o0 = mpb2[g], o1 = mpb2[32+g], o2 = mpb2[64+g], o3 = mpb2[96+g];
  for (int k = 0; k < 32; ++k) {
    float hk = c[i][k];
    o0 += hk * mpw2[k*128 +      g];
    o1 += hk * mpw2[k*128 + 32 + g];
    o2 += hk * mpw2[k*128 + 64 + g];
    o3 += hk * mpw2[k*128 + 96 + g];
  }
  if (ok) Aout4[n*32 + g] = make_float4(o0, o1, o2, o3 * a[i][g]);
}

// ---------------------------------------------------------------------------
// gather: barrier-free, 4 nodes/block, one wave64/node, lane=(hf,g).
// Round-4 proven structure: 4 edges per half-wave batched (8/wave in flight).
// Writes acc4[n*32+g] = (av0, av1, av2, acc_s).
// ---------------------------------------------------------------------------
#define EDGE_MATH(ED, M0, M1, FR, Av, V0, V1, V2)                         \
  {                                                                        \
    float ga = M0.x + FR*(M1.x - M0.x);                                    \
    float ca = M0.y + FR*(M1.y - M0.y);                                    \
    float da = M0.z + FR*(M1.z - M0.z);                                    \
    float sa = M0.w + FR*(M1.w - M0.w);                                    \
    float gates = ga*Av.x, cpg = ca*Av.y, sed = da*Av.z;                   \
    acc_s += sa*Av.w;                                                      \
    float crx = ED.y*vd2 - ED.z*vd1;                                       \
    float cry = ED.z*vd0 - ED.x*vd2;                                       \
    float crz = ED.x*vd1 - ED.y*vd0;                                       \
    av0 += sed*ED.x + gates*V0 + cpg*crx;                                  \
    av1 += sed*ED.y + gates*V1 + cpg*cry;                                  \
    av2 += sed*ED.z + gates*V2 + cpg*crz;                                  \
  }

__global__ __launch_bounds__(256) void gather_kernel(
    const int* __restrict__ off, const int* __restrict__ srcp,
    const float4* __restrict__ edata, const float4* __restrict__ tbl4,
    const float* __restrict__ v_prev, const float4* __restrict__ Aout4,
    float4* __restrict__ acc4, int N_)
{
  int tid = threadIdx.x, w = tid >> 6, lane = tid & 63, g = lane & 31, hf = lane >> 5;
  int n = blockIdx.x * 4 + w;
  if (n >= N_) return;                      // no barriers: early exit is safe
  const float* vp = v_prev + (long)n*96 + g*3;
  float vd0 = vp[0], vd1 = vp[1], vd2 = vp[2];
  int pstart = off[n], pend = off[n + 1];
  float acc_s = 0, av0 = 0, av1 = 0, av2 = 0;
  const float inv_step = (float)TBL / LEN_F;

  int deg = pend - pstart;
  int nfull = deg >> 3;                     // groups of 8 (4 per half)
  int pb = pstart + hf * 4;
  for (int it = 0; it < nfull; ++it, pb += 8) {
    int srcs[4]; float4 ed[4];
    #pragma unroll
    for (int b = 0; b < 4; ++b) { srcs[b] = srcp[pb + b]; ed[b] = edata[pb + b]; }
    float4 m0[4], m1[4], A[4]; float fr[4];
    float vs0[4], vs1[4], vs2[4];
    #pragma unroll
    for (int b = 0; b < 4; ++b) {
      float x = ed[b].w * inv_step;
      float f = floorf(x);
      int i0 = (int)f; if (i0 > TBL - 1) i0 = TBL - 1;
      fr[b] = x - f;
      m0[b] = tbl4[(long)i0*32 + g];
      m1[b] = tbl4[(long)(i0 + 1)*32 + g];
      A[b]  = Aout4[(long)srcs[b]*32 + g];
      const float* vq = v_prev + (long)srcs[b]*96 + g*3;
      vs0[b] = vq[0]; vs1[b] = vq[1]; vs2[b] = vq[2];
    }
    #pragma unroll
    for (int b = 0; b < 4; ++b)
      EDGE_MATH(ed[b], m0[b], m1[b], fr[b], A[b], vs0[b], vs1[b], vs2[b]);
  }
  // tail: up to 7 edges, 2 per half then 1
  int p = pstart + nfull * 8 + hf;
  for (; p + 2 < pend; p += 4) {
    int  s0_ = srcp[p], s1_ = srcp[p + 2];
    float4 e0 = edata[p], e1 = edata[p + 2];
    float x0 = e0.w * inv_step, x1 = e1.w * inv_step;
    float f0 = floorf(x0), f1 = floorf(x1);
    int i0 = (int)f0; if (i0 > TBL - 1) i0 = TBL - 1;
    int i1 = (int)f1; if (i1 > TBL - 1) i1 = TBL - 1;
    float r0 = x0 - f0, r1 = x1 - f1;
    float4 a0 = tbl4[(long)i0*32 + g], b0 = tbl4[(long)(i0+1)*32 + g];
    float4 a1 = tbl4[(long)i1*32 + g], b1 = tbl4[(long)(i1+1)*32 + g];
    float4 A0 = Aout4[(long)s0_*32 + g], A1 = Aout4[(long)s1_*32 + g];
    const float* vq0 = v_prev + (long)s0_*96 + g*3;
    const float* vq1 = v_prev + (long)s1_*96 + g*3;
    float u0 = vq0[0], u1 = vq0[1], u2 = vq0[2];
    float t0 = vq1[0], t1 = vq1[1], t2 = vq1[2];
    EDGE_MATH(e0, a0, b0, r0, A0, u0, u1, u2);
    EDGE_MATH(e1, a1, b1, r1, A1, t0, t1, t2);
  }
  if (p < pend) {
    int  s0_ = srcp[p];
    float4 e0 = edata[p];
    float x0 = e0.w * inv_step;
    float f0 = floorf(x0);
    int i0 = (int)f0; if (i0 > TBL - 1) i0 = TBL - 1;
    float r0 = x0 - f0;
    float4 a0 = tbl4[(long)i0*32 + g], b0 = tbl4[(long)(i0+1)*32 + g];
    float4 A0 = Aout4[(long)s0_*32 + g];
    const float* vq0 = v_prev + (long)s0_*96 + g*3;
    float u0 = vq0[0], u1 = vq0[1], u2 = vq0[2];
    EDGE_MATH(e0, a0, b0, r0, A0, u0, u1, u2);
  }
  av0   += __shfl_xor(av0, 32);
  av1   += __shfl_xor(av1, 32);
  av2   += __shfl_xor(av2, 32);
  acc_s += __shfl_xor(acc_s, 32);
  if (hf == 0) acc4[(long)n*32 + g] = make_float4(av0, av1, av2, acc_s);
}

// ---------------------------------------------------------------------------
// update (layer 0) + nodeA for layer 1 fused in tail; extra blocks do tbl l1.
// All LDS rows are half-wave-private -> no barriers (wave64 lockstep).
// ---------------------------------------------------------------------------
__global__ __launch_bounds__(256) void update_mid_kernel(
    const float* __restrict__ s_prev, const float* __restrict__ v_prev,
    const float4* __restrict__ acc4,
    const float* __restrict__ uU, const float* __restrict__ uV,
    const float* __restrict__ uw1, const float* __restrict__ ub1,
    const float* __restrict__ uw2, const float* __restrict__ ub2,
    const float* __restrict__ nw1, const float* __restrict__ nb1,
    const float* __restrict__ nw2, const float* __restrict__ nb2,
    const float* __restrict__ tw1, const float* __restrict__ tb1,
    const float* __restrict__ tw2, const float* __restrict__ tb2,
    float* __restrict__ s_out, float* __restrict__ v_out,
    float4* __restrict__ Aout4, float4* __restrict__ tbl4,
    int N_, int nodeBlocks)
{
  __shared__ float vld[8][96];
  __shared__ float in64[8][64];
  __shared__ float hld[8][32];
  int tid = threadIdx.x, i = tid >> 5, g = tid & 31;
  if (blockIdx.x >= nodeBlocks) {
    int t = (blockIdx.x - nodeBlocks) * 8 + i;
    mlp_tbl_block(i, g, t, tw1, tb1, tw2, tb2, tbl4, vld, hld);
    return;
  }
  long n = (long)blockIdx.x * 8 + i;
  bool ok = (n < N_);
  float nv0 = 0, nv1 = 0, nv2 = 0, ns = 0;
  if (ok) {
    float4 a = acc4[n*32 + g];
    const float* vp = v_prev + n*96 + g*3;
    nv0 = vp[0] + a.x; nv1 = vp[1] + a.y; nv2 = vp[2] + a.z;
    ns  = s_prev[n*32 + g] + a.w;
  }
  vld[i][g*3+0] = nv0; vld[i][g*3+1] = nv1; vld[i][g*3+2] = nv2;
  float Vv0=0,Vv1=0,Vv2=0,Uv0=0,Uv1=0,Uv2=0;
  for (int f = 0; f < 32; ++f) {
    float wu = uU[f*32 + g];
    float wv = uV[f*32 + g];
    float v0 = vld[i][f*3+0], v1 = vld[i][f*3+1], v2 = vld[i][f*3+2];
    Vv0 += v0*wv; Vv1 += v1*wv; Vv2 += v2*wv;
    Uv0 += v0*wu; Uv1 += v1*wu; Uv2 += v2*wu;
  }
  float Vn = sqrtf(Vv0*Vv0 + Vv1*Vv1 + Vv2*Vv2);
  in64[i][g] = Vn; in64[i][32 + g] = ns;
  float h = ub1[g];
  for (int k = 0; k < 64; ++k) h += in64[i][k] * uw1[k*32 + g];
  h = fsilu(h);
  hld[i][g] = h;
  float og = ub2[g], ossn = ub2[32 + g], oadd = ub2[64 + g];
  for (int k = 0; k < 32; ++k) {
    float hk = hld[i][k];
    og   += hk * uw2[k*96 +      g];
    ossn += hk * uw2[k*96 + 32 + g];
    oadd += hk * uw2[k*96 + 64 + g];
  }
  float s_fin = ns + Vn*Vn*ossn + oadd;
  if (ok) {
    float* vo = v_out + n*96 + g*3;
    vo[0] = nv0 + og*Uv0;
    vo[1] = nv1 + og*Uv1;
    vo[2] = nv2 + og*Uv2;
    s_out[n*32 + g] = s_fin;
  }
  // ---- nodeA for layer 1 (input = s_fin) ----
  in64[i][g] = s_fin;                          // reuse as x-stage
  float h2 = nb1[g];
  for (int k = 0; k < 32; ++k) h2 += in64[i][k] * nw1[k*32 + g];
  h2 = fsilu(h2);
  hld[i][g] = h2;
  float o0 = nb2[g], o1 = nb2[32+g], o2 = nb2[64+g], o3 = nb2[96+g];
  for (int k = 0; k < 32; ++k) {
    float hk = hld[i][k];
    o0 += hk * nw2[k*128 +      g];
    o1 += hk * nw2[k*128 + 32 + g];
    o2 += hk * nw2[k*128 + 64 + g];
    o3 += hk * nw2[k*128 + 96 + g];
  }
  if (ok) Aout4[n*32 + g] = make_float4(o0, o1, o2, o3 * s_fin);
}

// ---------------------------------------------------------------------------
// update (layer 1) + readout fused: writes d_out directly, never writes s/v.
// ---------------------------------------------------------------------------
__global__ __launch_bounds__(256) void update_final_kernel(
    const float* __restrict__ s_prev, const float* __restrict__ v_prev,
    const float4* __restrict__ acc4,
    const float* __restrict__ uU, const float* __restrict__ uV,
    const float* __restrict__ uw1, const float* __restrict__ ub1,
    const float* __restrict__ uw2, const float* __restrict__ ub2,
    const float* __restrict__ rw1, const float* __restrict__ rb1,
    const float* __restrict__ rw2, const float* __restrict__ rb2,
    const float* __restrict__ roV, float* __restrict__ out, int N_)
{
  __shared__ float vld[8][96];
  __shared__ float in64[8][64];
  __shared__ float hld[8][32];
  int tid = threadIdx.x, i = tid >> 5, g = tid & 31;
  long n = (long)blockIdx.x * 8 + i;
  bool ok = (n < N_);
  float nv0 = 0, nv1 = 0, nv2 = 0, ns = 0;
  if (ok) {
    float4 a = acc4[n*32 + g];
    const float* vp = v_prev + n*96 + g*3;
    nv0 = vp[0] + a.x; nv1 = vp[1] + a.y; nv2 = vp[2] + a.z;
    ns  = s_prev[n*32 + g] + a.w;
  }
  vld[i][g*3+0] = nv0; vld[i][g*3+1] = nv1; vld[i][g*3+2] = nv2;
  float Vv0=0,Vv1=0,Vv2=0,Uv0=0,Uv1=0,Uv2=0;
  for (int f = 0; f < 32; ++f) {
    float wu = uU[f*32 + g];
    float wv = uV[f*32 + g];
    float v0 = vld[i][f*3+0], v1 = vld[i][f*3+1], v2 = vld[i][f*3+2];
    Vv0 += v0*wv; Vv1 += v1*wv; Vv2 += v2*wv;
    Uv0 += v0*wu; Uv1 += v1*wu; Uv2 += v2*wu;
  }
  float Vn = sqrtf(Vv0*Vv0 + Vv1*Vv1 + Vv2*Vv2);
  in64[i][g] = Vn; in64[i][32 + g] = ns;
  float h = ub1[g];
  for (int k = 0; k < 64; ++k) h += in64[i][k] * uw1[k*32 + g];
  h = fsilu(h);
  hld[i][g] = h;
  float og = ub2[g], ossn = ub2[32 + g], oadd = ub2[64 + g];
  for (int k = 0; k < 32; ++k) {
    float hk = hld[i][k];
    og   += hk * uw2[k*96 +      g];
    ossn += hk * uw2[k*96 + 32 + g];
    oadd += hk * uw2[k*96 + 64 + g];
  }
  float s_fin = ns + Vn*Vn*ossn + oadd;
  float vf0 = nv0 + og*Uv0, vf1 = nv1 + og*Uv1, vf2 = nv2 + og*Uv2;
  // ---- readout ----
  in64[i][g] = s_fin;
  float h2 = rb1[g];
  for (int k = 0; k < 32; ++k) h2 += in64[i][k] * rw1[k*32 + g];
  h2 = fsilu(h2);
  hld[i][g] = h2;
  float inv = rb2[g], gate = rb2[32 + g];
  for (int k = 0; k < 32; ++k) {
    float hk = hld[i][k];
    inv  += hk * rw2[k*64 +      g];
    gate += hk * rw2[k*64 + 32 + g];
  }
  vld[i][g*3+0] = vf0; vld[i][g*3+1] = vf1; vld[i][g*3+2] = vf2;
  float R0 = 0, R1 = 0, R2 = 0;
  for (int f = 0; f < 32; ++f) {
    float wv = roV[f*32 + g];
    R0 += vld[i][f*3+0]*wv; R1 += vld[i][f*3+1]*wv; R2 += vld[i][f*3+2]*wv;
  }
  if (ok) {
    out[n*32 + g] = inv;
    long eb = (long)N_*32 + n*96 + (long)g*3;
    out[eb+0] = gate*R0; out[eb+1] = gate*R1; out[eb+2] = gate*R2;
  }
}

// ---------------------------------------------------------------------------
extern "C" void kernel_launch(void* const* d_in, const int* in_sizes, int n_in,
                              void* d_out, int out_size, void* d_ws, size_t ws_size,
                              hipStream_t stream)
{
  const float* s_in  = (const float*)d_in[0];
  const float* v_in  = (const float*)d_in[1];   // (N, F, 3)
  const int*   ei    = (const int*)  d_in[2];
  const float* dist  = (const float*)d_in[3];
  const float* edir  = (const float*)d_in[4];
  const float* mp_w1 = (const float*)d_in[5];
  const float* mp_b1 = (const float*)d_in[6];
  const float* mp_w2 = (const float*)d_in[7];
  const float* mp_b2 = (const float*)d_in[8];
  const float* mw_w1 = (const float*)d_in[9];
  const float* mw_b1 = (const float*)d_in[10];
  const float* mw_w2 = (const float*)d_in[11];
  const float* mw_b2 = (const float*)d_in[12];
  const float* u_U   = (const float*)d_in[13];
  const float* u_V   = (const float*)d_in[14];
  const float* u_w1  = (const float*)d_in[15];
  const float* u_b1  = (const float*)d_in[16];
  const float* u_w2  = (const float*)d_in[17];
  const float* u_b2  = (const float*)d_in[18];
  const float* ro_w1 = (const float*)d_in[19];
  const float* ro_b1 = (const float*)d_in[20];
  const float* ro_w2 = (const float*)d_in[21];
  const float* ro_b2 = (const float*)d_in[22];
  const float* ro_V  = (const float*)d_in[23];

  int N_ = in_sizes[0] / 32;
  int E_ = in_sizes[3];

  float*  sB    = (float*)d_ws;                       // N*32
  float*  vB    = sB + (size_t)N_*32;                 // N*96
  float4* Aout4 = (float4*)(vB + (size_t)N_*96);      // N*32 float4
  float4* acc4b = Aout4 + (size_t)N_*32;              // N*32 float4 (layer-1 acc)
  float4* tbl4  = acc4b + (size_t)N_*32;              // (TBL+1)*32 float4
  float4* edata = tbl4 + (size_t)(TBL+1)*32;          // E float4
  int*    srcp  = (int*)(edata + (size_t)E_);         // E
  int*    deg   = srcp + E_;                          // N
  int*    off   = deg + N_;                           // N+1
  int*    cursor= off + N_ + 1;                       // N

  // layer-0 acc scratch: d_out (N*32 float4) — fully dead before final write.
  float4* acc4a = (float4*)d_out;

  int nodeBlocks = (N_ + 7) / 8;
  int gathBlocks = (N_ + 3) / 4;
  int edgeBlocks = (E_ + 255) / 256;
  int tblBlocks  = (TBL + 1 + 7) / 8;

  // --- CSR build (once; edge_index constant across layers) ---
  hipMemsetAsync(deg, 0, (size_t)N_ * sizeof(int), stream);
  hist_kernel<<<edgeBlocks, 256, 0, stream>>>(ei, deg, E_);
  scan_kernel<<<1, 1024, 0, stream>>>(deg, off, cursor, N_);

  // --- prep: scatter + Aout(l0) + tbl(l0) overlapped in one launch ---
  prep_kernel<<<edgeBlocks + nodeBlocks + tblBlocks, 256, 0, stream>>>(
      ei, dist, edir, cursor, srcp, edata,
      s_in, mp_w1, mp_b1, mp_w2, mp_b2, mw_w1, mw_b1, mw_w2, mw_b2,
      Aout4, tbl4, N_, E_, edgeBlocks, nodeBlocks);

  gather_kernel<<<gathBlocks, 256, 0, stream>>>(
      off, srcp, edata, tbl4, v_in, Aout4, acc4a, N_);

  // --- update l0 + nodeA(l1) + tbl(l1) ---
  update_mid_kernel<<<nodeBlocks + tblBlocks, 256, 0, stream>>>(
      s_in, v_in, acc4a,
      u_U, u_V, u_w1, u_b1, u_w2, u_b2,
      mp_w1 + 1024, mp_b1 + 32, mp_w2 + 4096, mp_b2 + 128,
      mw_w1 + 1024, mw_b1 + 32, mw_w2 + 4096, mw_b2 + 128,
      sB, vB, Aout4, tbl4, N_, nodeBlocks);

  gather_kernel<<<gathBlocks, 256, 0, stream>>>(
      off, srcp, edata, tbl4, vB, Aout4, acc4b, N_);

  // --- update l1 + readout ---
  update_final_kernel<<<nodeBlocks, 256, 0, stream>>>(
      sB, vB, acc4b,
      u_U + 1024, u_V + 1024, u_w1 + 2048, u_b1 + 32, u_w2 + 3072, u_b2 + 96,
      ro_w1, ro_b1, ro_w2, ro_b2, ro_V, (float*)d_out, N_);
}